// Round 4
// baseline (233.653 us; speedup 1.0000x reference)
//
#include <hip/hip_runtime.h>

#define NDIM 4096
#define B_LG 256
#define B_SM 256
#define N_WID 128
#define R_LG 64
#define R_SM 16
#define BLOCK 512
#define MAXB 256            // bucket capacity per wid
#define MAXM_LG 6           // batches fused per large item (x: 6*1024*4 = 24 KB)
#define MAXM_SM 4           // batches fused per small item (x: 4*4096*4 = 64 KB)
#define PF 8                // float4 loads per software-pipeline group
#define OUT_SIZE (B_LG * R_LG + B_SM * R_SM)

// Equal-cost items: every item streams exactly 256 KB of A in 32 float4-iters.
//   large: (wid, group, d-quarter)  A = 1024x64x4  = 256 KB
//   small: (wid, group, full d)     A = 4096x16x4  = 256 KB
// x for the whole item staged ONCE -> one barrier, then the 256 KB A stream is
// straight-line (no barriers). Persistent blocks + global ticket balance the
// ~555 items across 512 slots; drain tail <= 1 item, >=50 active blocks keep
// HBM saturated (8 waves x 8 KB in flight each >> BW*latency = 2.4 MB chip).
#define DCH_LG 1024
#define DCH_SM 4096
#define GRID_MAIN 512

typedef float floatv4 __attribute__((ext_vector_type(4)));  // nt-load-compatible

// ---- workspace layout (int indices). Poisoned every iteration, so
//      setup_kernel initializes every word the main kernel reads. ----
#define WS_NWORK  0
#define WS_TICKET 1
#define WS_BKT_L  256
#define WS_BKT_S  (WS_BKT_L + N_WID * MAXB)
#define WS_WORK   (WS_BKT_S + N_WID * MAXB)   // item i at [WS_WORK+2i], [+2i+1]

// ------------- kernel 1: bucket batches by wid + build worklist + zero out --
__global__ __launch_bounds__(BLOCK)
void setup_kernel(const int* __restrict__ wids_l,
                  const int* __restrict__ wids_s,
                  int* __restrict__ ws,
                  float* __restrict__ out)
{
    __shared__ int cl[N_WID], cs[N_WID];
    __shared__ int nwork;
    const int t = threadIdx.x;
    if (t < N_WID) { cl[t] = 0; cs[t] = 0; }
    if (t == 0) nwork = 0;
    __syncthreads();
    if (t < B_LG) {
        const int w = wids_l[t];
        const int s = atomicAdd(&cl[w], 1);
        ws[WS_BKT_L + w * MAXB + s] = t;
    } else if (t < B_LG + B_SM) {
        const int b = t - B_LG;
        const int w = wids_s[b];
        const int s = atomicAdd(&cs[w], 1);
        ws[WS_BKT_S + w * MAXB + s] = b;
    }
    __syncthreads();
    if (t < N_WID) {
        // items: (class, wid, quarter, group-start, M)
        int cnt = cl[t];
        for (int g = 0; g < cnt; g += MAXM_LG) {
            const int Mi   = min(MAXM_LG, cnt - g);
            const int base = atomicAdd(&nwork, 4);
            for (int q = 0; q < 4; ++q) {               // large: 4 d-quarters
                ws[WS_WORK + 2 * (base + q)]     = (t << 8) | q;
                ws[WS_WORK + 2 * (base + q) + 1] = (g << 8) | Mi;
            }
        }
        cnt = cs[t];
        for (int g = 0; g < cnt; g += MAXM_SM) {
            const int Mi   = min(MAXM_SM, cnt - g);
            const int base = atomicAdd(&nwork, 1);      // small: one item
            ws[WS_WORK + 2 * base]     = (1 << 30) | (t << 8);
            ws[WS_WORK + 2 * base + 1] = (g << 8) | Mi;
        }
    }
    __syncthreads();
    if (t == 0) { ws[WS_NWORK] = nwork; ws[WS_TICKET] = 0; }
    for (int i = t; i < OUT_SIZE; i += BLOCK) out[i] = 0.0f;
}

// ------------- one equal-cost item: stage x once, stream 256 KB of A --------
template<int R, int M, int DCH>
__device__ __forceinline__ void gemv_item(
    const float* __restrict__ x,      // x rows base for this class
    const float* __restrict__ Ab,     // A[wid]
    float* __restrict__ outb,         // out base for this class
    const int* __restrict__ batches,  // M batch indices (uniform reads)
    int dbase,                        // d offset of this item's range
    float* __restrict__ xs,           // LDS, >= M*DCH floats
    float* __restrict__ red)          // LDS [8][16][4]
{
    constexpr int LPR  = R / 4;         // lanes per A-row: 16 (R=64) or 4 (R=16)
    constexpr int ROWS = BLOCK / LPR;   // A-rows per float4-iter: 32 or 128
    constexpr int IT   = DCH / ROWS;    // 32 for both classes
    constexpr int NG   = IT / PF;       // 4 pipeline groups
    static_assert(IT % PF == 0, "item not divisible by pipeline group");

    const int t = threadIdx.x;

    int rows[M];
#pragma unroll
    for (int m = 0; m < M; ++m) rows[m] = batches[m];

    // stage ALL x for this item, one barrier total
#pragma unroll
    for (int m = 0; m < M; ++m)
        for (int i = t; i < DCH / 4; i += BLOCK)
            reinterpret_cast<float4*>(xs + m * DCH)[i] =
                reinterpret_cast<const float4*>(x + (size_t)rows[m] * NDIM + dbase)[i];
    __syncthreads();

    const int d_sub  = t / LPR;
    const int r_base = (t % LPR) * 4;
    const float* Abt = Ab + ((size_t)dbase + d_sub) * R + r_base;

    float acc[M][4];
#pragma unroll
    for (int m = 0; m < M; ++m)
#pragma unroll
        for (int j = 0; j < 4; ++j) acc[m][j] = 0.0f;

    // Straight-line: NG groups of PF nontemporal float4 loads + FMAs; the
    // scheduler overlaps group g+1 loads with group g FMAs (fine vmcnt, no
    // barriers anywhere inside the 256 KB stream).
#pragma unroll
    for (int g = 0; g < NG; ++g) {
        floatv4 buf[PF];
#pragma unroll
        for (int p = 0; p < PF; ++p)
            buf[p] = __builtin_nontemporal_load(
                reinterpret_cast<const floatv4*>(Abt + (size_t)(g * PF + p) * ROWS * R));
#pragma unroll
        for (int p = 0; p < PF; ++p) {
            const int d = (g * PF + p) * ROWS + d_sub;
#pragma unroll
            for (int m = 0; m < M; ++m) {
                const float xv = xs[m * DCH + d];
                acc[m][0] = fmaf(xv, buf[p].x, acc[m][0]);
                acc[m][1] = fmaf(xv, buf[p].y, acc[m][1]);
                acc[m][2] = fmaf(xv, buf[p].z, acc[m][2]);
                acc[m][3] = fmaf(xv, buf[p].w, acc[m][3]);
            }
        }
    }

    // reduce once per item: shuffle in wave, LDS across 8 waves, atomicAdd
    const int wave = t >> 6;
    const int lane = t & 63;
#pragma unroll
    for (int m = 0; m < M; ++m)
#pragma unroll
        for (int off = 32; off >= LPR; off >>= 1)
#pragma unroll
            for (int j = 0; j < 4; ++j)
                acc[m][j] += __shfl_down(acc[m][j], off, 64);

#pragma unroll
    for (int m = 0; m < M; ++m) {
        __syncthreads();
        if (lane < LPR)
#pragma unroll
            for (int j = 0; j < 4; ++j) red[(wave * 16 + lane) * 4 + j] = acc[m][j];
        __syncthreads();
        if (t < R) {
            const int rl = t / 4, j = t % 4;
            float v = 0.0f;
#pragma unroll
            for (int w = 0; w < 8; ++w) v += red[(w * 16 + rl) * 4 + j];
            atomicAdd(outb + (size_t)rows[m] * R + t, v);
        }
    }
}

// ------------- kernel 2: persistent blocks + ticket over equal items --------
__global__ __launch_bounds__(BLOCK, 4)
void SequentialLoraA_kernel(const float* __restrict__ x,
                            const float* __restrict__ Al,
                            const float* __restrict__ As,
                            float* __restrict__ out,
                            int* __restrict__ ws)
{
    __shared__ float xs[MAXM_SM * DCH_SM];  // 64 KB (worst case: small, M=4)
    __shared__ float red[8 * 16 * 4];       // 2 KB
    __shared__ int s_item;

    const int t  = threadIdx.x;
    const int nw = ws[WS_NWORK];

    for (;;) {
        __syncthreads();   // (a) previous item's xs/red reads done; s_item free
        if (t == 0) s_item = atomicAdd(ws + WS_TICKET, 1);
        __syncthreads();   // (b) s_item visible
        const int it = s_item;
        if (it >= nw) return;

        const int a   = ws[WS_WORK + 2 * it];
        const int b   = ws[WS_WORK + 2 * it + 1];
        const int wid = (a >> 8) & 0x7f;
        const int Mi  = b & 0xff;
        const int gs  = b >> 8;

        if (a & (1 << 30)) {  // small class: full d, M<=4
            const float* xb  = x + (size_t)B_LG * NDIM;
            const float* Ab  = As + (size_t)wid * NDIM * R_SM;
            float*       ob  = out + (size_t)B_LG * R_LG;
            const int*   bkt = ws + WS_BKT_S + wid * MAXB + gs;
            switch (Mi) {
              case 1:  gemv_item<R_SM, 1, DCH_SM>(xb, Ab, ob, bkt, 0, xs, red); break;
              case 2:  gemv_item<R_SM, 2, DCH_SM>(xb, Ab, ob, bkt, 0, xs, red); break;
              case 3:  gemv_item<R_SM, 3, DCH_SM>(xb, Ab, ob, bkt, 0, xs, red); break;
              default: gemv_item<R_SM, 4, DCH_SM>(xb, Ab, ob, bkt, 0, xs, red); break;
            }
        } else {              // large class: d-quarter, M<=6
            const int dbase = (a & 0xff) * DCH_LG;
            const float* Ab  = Al + (size_t)wid * NDIM * R_LG;
            const int*   bkt = ws + WS_BKT_L + wid * MAXB + gs;
            switch (Mi) {
              case 1:  gemv_item<R_LG, 1, DCH_LG>(x, Ab, out, bkt, dbase, xs, red); break;
              case 2:  gemv_item<R_LG, 2, DCH_LG>(x, Ab, out, bkt, dbase, xs, red); break;
              case 3:  gemv_item<R_LG, 3, DCH_LG>(x, Ab, out, bkt, dbase, xs, red); break;
              case 4:  gemv_item<R_LG, 4, DCH_LG>(x, Ab, out, bkt, dbase, xs, red); break;
              case 5:  gemv_item<R_LG, 5, DCH_LG>(x, Ab, out, bkt, dbase, xs, red); break;
              default: gemv_item<R_LG, 6, DCH_LG>(x, Ab, out, bkt, dbase, xs, red); break;
            }
        }
    }
}

extern "C" void kernel_launch(void* const* d_in, const int* in_sizes, int n_in,
                              void* d_out, int out_size, void* d_ws, size_t ws_size,
                              hipStream_t stream) {
    const float* x      = (const float*)d_in[0];
    const int*   wids_l = (const int*)d_in[1];
    const int*   wids_s = (const int*)d_in[2];
    const float* Al     = (const float*)d_in[3];
    const float* As     = (const float*)d_in[4];
    float* out = (float*)d_out;
    int*   ws  = (int*)d_ws;

    setup_kernel<<<1, BLOCK, 0, stream>>>(wids_l, wids_s, ws, out);
    SequentialLoraA_kernel<<<GRID_MAIN, BLOCK, 0, stream>>>(x, Al, As, out, ws);
}

// Round 5
// 215.743 us; speedup vs baseline: 1.0830x; 1.0830x over previous
//
#include <hip/hip_runtime.h>

#define NDIM 4096
#define B_LG 256
#define B_SM 256
#define N_WID 128
#define R_LG 64
#define R_SM 16
#define BLOCK 512
#define MAXB 256           // bucket capacity per wid
#define MAXM 6             // max batches fused per item
#define PF 8               // float4 loads per software-pipeline group
#define OUT_SIZE (B_LG * R_LG + B_SM * R_SM)

// R3 structure (best measured: 216.5us) + ONE change: large items stage x once
// per d-half (48 KB LDS, ONE barrier) then stream 512 KB of A straight-line
// with zero barriers. Small class byte-identical to R3. Static single-round
// map: worst-case items = 2*149 large-halves + 149 small = 447 <= 512 slots.
#define DHALF_LG 2048              // large item d-range (half), stage-once
#define DCH_SM 1024                // small chunk rows (ROWS=128, IT=8, NG=1)
#define NCH_SM 4                   // small chunks (covers all 4096 of d)
#define GRID_MAIN 512

typedef float floatv4 __attribute__((ext_vector_type(4)));  // nt-load-compatible

// ---- workspace layout (ints). Poisoned every iteration by the harness, so
//      setup_kernel initializes every word the main kernel reads. ----
#define WS_NWORK  0
#define WS_BKT_L  256
#define WS_BKT_S  (WS_BKT_L + N_WID * MAXB)
#define WS_WORK   (WS_BKT_S + N_WID * MAXB)   // item i at [WS_WORK+2i], [+2i+1]

// ------------- kernel 1: bucket batches by wid + build worklist + zero out --
__global__ __launch_bounds__(BLOCK)
void setup_kernel(const int* __restrict__ wids_l,
                  const int* __restrict__ wids_s,
                  int* __restrict__ ws,
                  float* __restrict__ out)
{
    __shared__ int cl[N_WID], cs[N_WID];
    __shared__ int nwork;
    const int t = threadIdx.x;
    if (t < N_WID) { cl[t] = 0; cs[t] = 0; }
    if (t == 0) nwork = 0;
    __syncthreads();
    if (t < B_LG) {
        const int w = wids_l[t];
        const int s = atomicAdd(&cl[w], 1);
        ws[WS_BKT_L + w * MAXB + s] = t;
    } else if (t < B_LG + B_SM) {
        const int b = t - B_LG;
        const int w = wids_s[b];
        const int s = atomicAdd(&cs[w], 1);
        ws[WS_BKT_S + w * MAXB + s] = b;
    }
    __syncthreads();
    if (t < N_WID) {
        // emit work items: (class, wid, d-half, group-start, M)
        int cnt = cl[t];
        for (int g = 0; g < cnt; g += MAXM) {
            const int Mi   = min(MAXM, cnt - g);
            const int base = atomicAdd(&nwork, 2);
            for (int h = 0; h < 2; ++h) {               // large: 2 d-halves
                ws[WS_WORK + 2 * (base + h)]     = (t << 8) | h;
                ws[WS_WORK + 2 * (base + h) + 1] = (g << 8) | Mi;
            }
        }
        cnt = cs[t];
        for (int g = 0; g < cnt; g += MAXM) {
            const int Mi   = min(MAXM, cnt - g);
            const int base = atomicAdd(&nwork, 1);      // small: one item
            ws[WS_WORK + 2 * base]     = (1 << 30) | (t << 8);
            ws[WS_WORK + 2 * base + 1] = (g << 8) | Mi;
        }
    }
    __syncthreads();
    if (t == 0) ws[WS_NWORK] = nwork;
    for (int i = t; i < OUT_SIZE; i += BLOCK) out[i] = 0.0f;
}

// ------------- shared epilogue: block-wide reduce + atomicAdd ---------------
template<int R, int M>
__device__ __forceinline__ void reduce_store(
    float (*acc)[4], const int* rows, float* __restrict__ outb,
    float* __restrict__ red)
{
    constexpr int LPR = R / 4;
    const int t    = threadIdx.x;
    const int wave = t >> 6;
    const int lane = t & 63;
#pragma unroll
    for (int m = 0; m < M; ++m)
#pragma unroll
        for (int off = 32; off >= LPR; off >>= 1)
#pragma unroll
            for (int j = 0; j < 4; ++j)
                acc[m][j] += __shfl_down(acc[m][j], off, 64);

#pragma unroll
    for (int m = 0; m < M; ++m) {
        __syncthreads();
        if (lane < LPR)
#pragma unroll
            for (int j = 0; j < 4; ++j) red[(wave * 16 + lane) * 4 + j] = acc[m][j];
        __syncthreads();
        if (t < R) {
            const int rl = t / 4, j = t % 4;
            float v = 0.0f;
#pragma unroll
            for (int w = 0; w < 8; ++w) v += red[(w * 16 + rl) * 4 + j];
            atomicAdd(outb + (size_t)rows[m] * R + t, v);
        }
    }
}

// ------------- large item: stage x once, stream 512 KB of A barrier-free ----
template<int M>
__device__ __forceinline__ void gemv_large(
    const float* __restrict__ x, const float* __restrict__ Ab,
    float* __restrict__ outb, const int* __restrict__ batches,
    int dbase, float* __restrict__ xs, float* __restrict__ red)
{
    constexpr int R    = R_LG;
    constexpr int LPR  = R / 4;              // 16
    constexpr int ROWS = BLOCK / LPR;        // 32
    constexpr int IT   = DHALF_LG / ROWS;    // 64
    constexpr int NG   = IT / PF;            // 8

    const int t = threadIdx.x;
    int rows[M];
#pragma unroll
    for (int m = 0; m < M; ++m) rows[m] = batches[m];

    // stage x for the WHOLE half: M float4 loads/thread, ONE barrier
#pragma unroll
    for (int m = 0; m < M; ++m)
        for (int i = t; i < DHALF_LG / 4; i += BLOCK)
            reinterpret_cast<float4*>(xs + m * DHALF_LG)[i] =
                reinterpret_cast<const float4*>(x + (size_t)rows[m] * NDIM + dbase)[i];
    __syncthreads();

    const int d_sub  = t / LPR;
    const int r_base = (t % LPR) * 4;
    const float* Abt = Ab + ((size_t)dbase + d_sub) * R + r_base;

    float acc[M][4];
#pragma unroll
    for (int m = 0; m < M; ++m)
#pragma unroll
        for (int j = 0; j < 4; ++j) acc[m][j] = 0.0f;

    // 512 KB straight-line: NG groups of PF nontemporal float4 loads + FMAs,
    // zero barriers; scheduler overlaps group g+1 loads with group g FMAs.
#pragma unroll
    for (int g = 0; g < NG; ++g) {
        floatv4 buf[PF];
#pragma unroll
        for (int p = 0; p < PF; ++p)
            buf[p] = __builtin_nontemporal_load(
                reinterpret_cast<const floatv4*>(Abt + (size_t)(g * PF + p) * ROWS * R));
#pragma unroll
        for (int p = 0; p < PF; ++p) {
            const int d = (g * PF + p) * ROWS + d_sub;
#pragma unroll
            for (int m = 0; m < M; ++m) {
                const float xv = xs[m * DHALF_LG + d];
                acc[m][0] = fmaf(xv, buf[p].x, acc[m][0]);
                acc[m][1] = fmaf(xv, buf[p].y, acc[m][1]);
                acc[m][2] = fmaf(xv, buf[p].z, acc[m][2]);
                acc[m][3] = fmaf(xv, buf[p].w, acc[m][3]);
            }
        }
    }
    reduce_store<R, M>(acc, rows, outb, red);
}

// ------------- small item: R3-identical chunked path ------------------------
template<int M>
__device__ __forceinline__ void gemv_small(
    const float* __restrict__ x, const float* __restrict__ Ab,
    float* __restrict__ outb, const int* __restrict__ batches,
    float* __restrict__ xs, float* __restrict__ red)
{
    constexpr int R    = R_SM;
    constexpr int LPR  = R / 4;              // 4
    constexpr int ROWS = BLOCK / LPR;        // 128
    constexpr int IT   = DCH_SM / ROWS;      // 8
    constexpr int NG   = IT / PF;            // 1

    const int t = threadIdx.x;
    int rows[M];
#pragma unroll
    for (int m = 0; m < M; ++m) rows[m] = batches[m];

    const int d_sub  = t / LPR;
    const int r_base = (t % LPR) * 4;

    float acc[M][4];
#pragma unroll
    for (int m = 0; m < M; ++m)
#pragma unroll
        for (int j = 0; j < 4; ++j) acc[m][j] = 0.0f;

    for (int c = 0; c < NCH_SM; ++c) {
        const int d0 = c * DCH_SM;
        __syncthreads();  // previous chunk's xs reads finished
#pragma unroll
        for (int m = 0; m < M; ++m)
            for (int i = t; i < DCH_SM / 4; i += BLOCK)
                reinterpret_cast<float4*>(xs + m * DCH_SM)[i] =
                    reinterpret_cast<const float4*>(x + (size_t)rows[m] * NDIM + d0)[i];
        __syncthreads();

        const float* Abt = Ab + ((size_t)d0 + d_sub) * R + r_base;
#pragma unroll
        for (int g = 0; g < NG; ++g) {
            floatv4 buf[PF];
#pragma unroll
            for (int p = 0; p < PF; ++p)
                buf[p] = __builtin_nontemporal_load(
                    reinterpret_cast<const floatv4*>(Abt + (size_t)(g * PF + p) * ROWS * R));
#pragma unroll
            for (int p = 0; p < PF; ++p) {
                const int d = (g * PF + p) * ROWS + d_sub;
#pragma unroll
                for (int m = 0; m < M; ++m) {
                    const float xv = xs[m * DCH_SM + d];
                    acc[m][0] = fmaf(xv, buf[p].x, acc[m][0]);
                    acc[m][1] = fmaf(xv, buf[p].y, acc[m][1]);
                    acc[m][2] = fmaf(xv, buf[p].z, acc[m][2]);
                    acc[m][3] = fmaf(xv, buf[p].w, acc[m][3]);
                }
            }
        }
    }
    reduce_store<R, M>(acc, rows, outb, red);
}

// ------------- kernel 2: static item map, one block per item ----------------
__global__ __launch_bounds__(BLOCK, 4)
void SequentialLoraA_kernel(const float* __restrict__ x,
                            const float* __restrict__ Al,
                            const float* __restrict__ As,
                            float* __restrict__ out,
                            const int* __restrict__ ws)
{
    __shared__ float xs[MAXM * DHALF_LG];  // 48 KB (large stage-once; small uses 24 KB)
    __shared__ float red[8 * 16 * 4];      // 2 KB

    const int it = blockIdx.x;
    if (it >= ws[WS_NWORK]) return;

    const int a   = ws[WS_WORK + 2 * it];
    const int b   = ws[WS_WORK + 2 * it + 1];
    const int wid = (a >> 8) & 0x7f;
    const int Mi  = b & 0xff;
    const int gs  = b >> 8;

    if (a & (1 << 30)) {  // small class: full d-range, 4 chunks of 1024
        const float* xb  = x + (size_t)B_LG * NDIM;
        const float* Ab  = As + (size_t)wid * NDIM * R_SM;
        float*       ob  = out + (size_t)B_LG * R_LG;
        const int*   bkt = ws + WS_BKT_S + wid * MAXB + gs;
        switch (Mi) {
          case 1:  gemv_small<1>(xb, Ab, ob, bkt, xs, red); break;
          case 2:  gemv_small<2>(xb, Ab, ob, bkt, xs, red); break;
          case 3:  gemv_small<3>(xb, Ab, ob, bkt, xs, red); break;
          case 4:  gemv_small<4>(xb, Ab, ob, bkt, xs, red); break;
          case 5:  gemv_small<5>(xb, Ab, ob, bkt, xs, red); break;
          default: gemv_small<6>(xb, Ab, ob, bkt, xs, red); break;
        }
    } else {              // large class: d-half, stage-once + barrier-free stream
        const int dbase = (a & 1) * DHALF_LG;
        const float* Ab  = Al + (size_t)wid * NDIM * R_LG;
        const int*   bkt = ws + WS_BKT_L + wid * MAXB + gs;
        switch (Mi) {
          case 1:  gemv_large<1>(x, Ab, out, bkt, dbase, xs, red); break;
          case 2:  gemv_large<2>(x, Ab, out, bkt, dbase, xs, red); break;
          case 3:  gemv_large<3>(x, Ab, out, bkt, dbase, xs, red); break;
          case 4:  gemv_large<4>(x, Ab, out, bkt, dbase, xs, red); break;
          case 5:  gemv_large<5>(x, Ab, out, bkt, dbase, xs, red); break;
          default: gemv_large<6>(x, Ab, out, bkt, dbase, xs, red); break;
        }
    }
}

extern "C" void kernel_launch(void* const* d_in, const int* in_sizes, int n_in,
                              void* d_out, int out_size, void* d_ws, size_t ws_size,
                              hipStream_t stream) {
    const float* x      = (const float*)d_in[0];
    const int*   wids_l = (const int*)d_in[1];
    const int*   wids_s = (const int*)d_in[2];
    const float* Al     = (const float*)d_in[3];
    const float* As     = (const float*)d_in[4];
    float* out = (float*)d_out;
    int*   ws  = (int*)d_ws;

    setup_kernel<<<1, BLOCK, 0, stream>>>(wids_l, wids_s, ws, out);
    SequentialLoraA_kernel<<<GRID_MAIN, BLOCK, 0, stream>>>(x, Al, As, out, ws);
}